// Round 4
// baseline (7381.377 us; speedup 1.0000x reference)
//
#include <hip/hip_runtime.h>
#include <math.h>

#define NPTS 4096
#define NBATCH 4
#define NTOT (NBATCH*NPTS)
#define KNN 20

__device__ __forceinline__ float lrelu_f(float h) { return h >= 0.f ? h : 0.2f * h; }

// ---------------- x:(B,6,N) -> xyzT:(B*N,6) ----------------
__global__ __launch_bounds__(256) void k_transpose_in(const float* __restrict__ x, float* __restrict__ xyzT)
{
    int p = blockIdx.x * 256 + threadIdx.x;
    if (p >= NTOT) return;
    int b = p >> 12, n = p & (NPTS - 1);
    #pragma unroll
    for (int c = 0; c < 6; ++c)
        xyzT[(size_t)p * 6 + c] = x[((size_t)b * 6 + c) * NPTS + n];
}

// ---------------- row squared norms ----------------
__global__ __launch_bounds__(256) void k_row_norms(const float* __restrict__ f, int stride, int C, float* __restrict__ xx)
{
    int p = blockIdx.x * 256 + threadIdx.x;
    if (p >= NTOT) return;
    const float* r = f + (size_t)p * stride;
    float s = 0.f;
    for (int c = 0; c < C; ++c) { float v = r[c]; s += v * v; }
    xx[p] = s;
}

// ---------------- weight transpose (O,CK) -> (CK,O) ----------------
__global__ __launch_bounds__(256) void k_transpose_w(const float* __restrict__ w, float* __restrict__ wt, int O, int CK)
{
    int e = blockIdx.x * 256 + threadIdx.x;
    if (e >= O * CK) return;
    int c = e / O, o = e - c * O;
    wt[e] = w[(size_t)o * CK + c];
}

// ---------------- kNN: one block per query point ----------------
// pd = 2*dot(q,c) - ||q||^2 - ||c||^2 ; top-20 largest, ties -> lower index
template<int C>
__global__ __launch_bounds__(256) void k_knn(
    const float* __restrict__ feat, int fstride,
    const float* __restrict__ xx,
    int* __restrict__ idx_out)
{
    constexpr int CP = (C + 3) & ~3;
    __shared__ __align__(16) float sq[CP];
    __shared__ float svals[256 * 17];
    __shared__ int   sinds[256 * 17];
    int p = blockIdx.x;
    int b = p >> 12;
    int tid = threadIdx.x;
    const float* qrow = feat + (size_t)p * fstride;
    for (int e = tid; e < C; e += 256) sq[e] = qrow[e];
    __syncthreads();
    float xxq = xx[p];
    const float* fb = feat + (size_t)b * NPTS * fstride;
    const float* xb = xx + b * NPTS;

    // each thread streams 16 candidates, keeps all 16 sorted descending
    float lv[16]; int li[16];
    #pragma unroll
    for (int j = 0; j < 16; ++j) { lv[j] = -INFINITY; li[j] = -1; }
    for (int it = 0; it < 16; ++it) {
        int cand = it * 256 + tid;
        const float* row = fb + (size_t)cand * fstride;
        float dot = 0.f;
        if constexpr ((C & 3) == 0) {
            #pragma unroll
            for (int c4 = 0; c4 < C / 4; ++c4) {
                float4 rv = *(const float4*)(row + 4 * c4);
                float4 qv = *(const float4*)(sq + 4 * c4);
                dot += rv.x * qv.x + rv.y * qv.y + rv.z * qv.z + rv.w * qv.w;
            }
        } else {
            #pragma unroll
            for (int c = 0; c < C; ++c) dot += sq[c] * row[c];
        }
        float cv = 2.f * dot - xxq - xb[cand];
        int ci = cand;
        // strict-greater keeps stable order => equal values keep lower index first
        #pragma unroll
        for (int j = 0; j < 16; ++j) {
            if (cv > lv[j]) {
                float tf = lv[j]; lv[j] = cv; cv = tf;
                int   ti = li[j]; li[j] = ci; ci = ti;
            }
        }
    }
    #pragma unroll
    for (int j = 0; j < 16; ++j) { svals[tid * 17 + j] = lv[j]; sinds[tid * 17 + j] = li[j]; }
    __syncthreads();

    // wave 0 merges the 256 sorted lists: 20 pop rounds
    if (tid < 64) {
        int h0 = 0, h1 = 0, h2 = 0, h3 = 0;
        int base = tid * 4;
        #pragma unroll 1
        for (int r = 0; r < KNN; ++r) {
            float bv = -INFINITY; int bi = 0x7fffffff; int bl = -1;
            if (h0 < 16) { float v = svals[(base+0)*17 + h0]; int ii = sinds[(base+0)*17 + h0]; if (v > bv || (v == bv && ii < bi)) { bv = v; bi = ii; bl = base+0; } }
            if (h1 < 16) { float v = svals[(base+1)*17 + h1]; int ii = sinds[(base+1)*17 + h1]; if (v > bv || (v == bv && ii < bi)) { bv = v; bi = ii; bl = base+1; } }
            if (h2 < 16) { float v = svals[(base+2)*17 + h2]; int ii = sinds[(base+2)*17 + h2]; if (v > bv || (v == bv && ii < bi)) { bv = v; bi = ii; bl = base+2; } }
            if (h3 < 16) { float v = svals[(base+3)*17 + h3]; int ii = sinds[(base+3)*17 + h3]; if (v > bv || (v == bv && ii < bi)) { bv = v; bi = ii; bl = base+3; } }
            #pragma unroll
            for (int off = 32; off > 0; off >>= 1) {
                float ov = __shfl_xor(bv, off);
                int   oi = __shfl_xor(bi, off);
                int   ol = __shfl_xor(bl, off);
                if (ov > bv || (ov == bv && oi < bi)) { bv = ov; bi = oi; bl = ol; }
            }
            if (tid == 0) idx_out[(size_t)p * KNN + r] = bi;
            if ((bl >> 2) == tid) {
                int u = bl & 3;
                h0 += (u == 0); h1 += (u == 1); h2 += (u == 2); h3 += (u == 3);
            }
        }
    }
}

// ---------------- edge conv: one block per point ----------------
// out[o] = lrelu( s[o]*(dot_sel + q[o]) + d[o] ),  dot_sel = max_k (s>=0) or min_k (s<0)
template<int C, int O>
__global__ __launch_bounds__(256) void k_edge_conv(
    const float* __restrict__ in, int istride,
    const int* __restrict__ idx,
    const float* __restrict__ wt,   // (2C, O) transposed weights
    const float* __restrict__ gg, const float* __restrict__ bb,
    const float* __restrict__ mm, const float* __restrict__ vv,
    float* __restrict__ out, int ostride)
{
    constexpr int G = 256 / O;
    constexpr int KPT = KNN / G;
    __shared__ int   sidx[KNN];
    __shared__ float sctr[C];
    __shared__ float snbr[KNN][C];
    __shared__ float sred[2][256];
    int p = blockIdx.x;
    int b = p >> 12;
    int tid = threadIdx.x;
    const float* ctr_row = in + (size_t)p * istride;
    if (tid < KNN) sidx[tid] = idx[(size_t)p * KNN + tid];
    for (int e = tid; e < C; e += 256) sctr[e] = ctr_row[e];
    __syncthreads();
    for (int e = tid; e < KNN * C; e += 256) {
        int k = e / C, c = e - k * C;
        snbr[k][c] = in[((size_t)b * NPTS + sidx[k]) * istride + c];
    }
    __syncthreads();
    int o = tid % O, gid = tid / O;
    float q = 0.f;
    #pragma unroll 4
    for (int c = 0; c < C; ++c) q += (wt[(C + c) * O + o] - wt[c * O + o]) * sctr[c];
    float acc[KPT];
    #pragma unroll
    for (int k = 0; k < KPT; ++k) acc[k] = 0.f;
    #pragma unroll 4
    for (int c = 0; c < C; ++c) {
        float wv = wt[c * O + o];
        #pragma unroll
        for (int k = 0; k < KPT; ++k) acc[k] += wv * snbr[gid * KPT + k][c];
    }
    float mx = -INFINITY, mn = INFINITY;
    #pragma unroll
    for (int k = 0; k < KPT; ++k) { mx = fmaxf(mx, acc[k]); mn = fminf(mn, acc[k]); }
    sred[0][tid] = mx; sred[1][tid] = mn;
    __syncthreads();
    if (gid == 0) {
        #pragma unroll
        for (int g2 = 1; g2 < G; ++g2) { mx = fmaxf(mx, sred[0][g2 * O + o]); mn = fminf(mn, sred[1][g2 * O + o]); }
        float s = gg[o] * rsqrtf(vv[o] + 1e-5f);
        float d = bb[o] - mm[o] * s;
        float dotv = (s >= 0.f) ? mx : mn;
        float h = s * (dotv + q) + d;
        out[(size_t)p * ostride + o] = lrelu_f(h);
    }
}

// ---------------- color MLP (3 -> 64) ----------------
__global__ __launch_bounds__(256) void k_color(
    const float* __restrict__ xyzT,
    const float* __restrict__ w,
    const float* __restrict__ gg, const float* __restrict__ bb,
    const float* __restrict__ mm, const float* __restrict__ vv,
    float* __restrict__ out, int ostride)
{
    int t = blockIdx.x * 256 + threadIdx.x;
    int p = t >> 6, o = t & 63;
    if (p >= NTOT) return;
    const float* rgb = xyzT + (size_t)p * 6 + 3;
    float h = rgb[0] * w[o*3+0] + rgb[1] * w[o*3+1] + rgb[2] * w[o*3+2];
    float s = gg[o] * rsqrtf(vv[o] + 1e-5f);
    float d = bb[o] - mm[o] * s;
    out[(size_t)p * ostride + o] = lrelu_f(s * h + d);
}

// ---------------- fp32 tiled GEMM: out[m][o] = act( A[m][:] . W[o][:] ) ----------------
__global__ __launch_bounds__(256) void k_gemm(
    const float* __restrict__ A, int lda,
    const float* __restrict__ W,
    const float* __restrict__ gg, const float* __restrict__ bb,
    const float* __restrict__ mm, const float* __restrict__ vv,
    int bn_act,
    float* __restrict__ out, int ldo,
    int K, int O)
{
    __shared__ __align__(16) float As[16][68];
    __shared__ __align__(16) float Bs[16][68];
    int tid = threadIdx.x;
    int tM = blockIdx.x * 64;
    int tN = blockIdx.y * 64;
    int lk = tid & 15, lr = tid >> 4;
    float acc[4][4];
    #pragma unroll
    for (int i = 0; i < 4; ++i)
        #pragma unroll
        for (int j = 0; j < 4; ++j) acc[i][j] = 0.f;

    for (int k0 = 0; k0 < K; k0 += 16) {
        #pragma unroll
        for (int i = 0; i < 4; ++i) {
            int r = lr + 16 * i;
            As[lk][r] = A[(size_t)(tM + r) * lda + k0 + lk];
        }
        #pragma unroll
        for (int i = 0; i < 4; ++i) {
            int r = lr + 16 * i;
            int oo = tN + r;
            Bs[lk][r] = (oo < O) ? W[(size_t)oo * K + k0 + lk] : 0.f;
        }
        __syncthreads();
        #pragma unroll
        for (int kk = 0; kk < 16; ++kk) {
            float4 av = *(const float4*)&As[kk][lr * 4];
            float4 bv = *(const float4*)&Bs[kk][lk * 4];
            float a0 = av.x, a1 = av.y, a2 = av.z, a3 = av.w;
            float b0 = bv.x, b1 = bv.y, b2 = bv.z, b3 = bv.w;
            acc[0][0] += a0*b0; acc[0][1] += a0*b1; acc[0][2] += a0*b2; acc[0][3] += a0*b3;
            acc[1][0] += a1*b0; acc[1][1] += a1*b1; acc[1][2] += a1*b2; acc[1][3] += a1*b3;
            acc[2][0] += a2*b0; acc[2][1] += a2*b1; acc[2][2] += a2*b2; acc[2][3] += a2*b3;
            acc[3][0] += a3*b0; acc[3][1] += a3*b1; acc[3][2] += a3*b2; acc[3][3] += a3*b3;
        }
        __syncthreads();
    }
    int ty = lr, tx = lk;
    #pragma unroll
    for (int i = 0; i < 4; ++i) {
        int m = tM + ty * 4 + i;
        #pragma unroll
        for (int j = 0; j < 4; ++j) {
            int oo = tN + tx * 4 + j;
            if (oo < O) {
                float t = acc[i][j];
                if (bn_act) {
                    float s = gg[oo] * rsqrtf(vv[oo] + 1e-5f);
                    float d = bb[oo] - mm[oo] * s;
                    t = s * t + d;
                    t = t >= 0.f ? t : 0.2f * t;
                } else {
                    t += bb[oo];
                }
                out[(size_t)m * ldo + oo] = t;
            }
        }
    }
}

// ---------------- x5 (B*N,1024 cols of xcomb) -> d_out (B,1024,N) ----------------
__global__ __launch_bounds__(256) void k_transpose_x5(const float* __restrict__ xcomb, float* __restrict__ out_x5)
{
    __shared__ float t[64][65];
    int tM = blockIdx.x * 64;
    int tO = blockIdx.y * 64;
    int tid = threadIdx.x;
    #pragma unroll
    for (int i = 0; i < 16; ++i) {
        int e = tid + 256 * i;
        int rr = e >> 6, cc = e & 63;
        t[rr][cc] = xcomb[(size_t)(tM + rr) * 1408 + 384 + tO + cc];
    }
    __syncthreads();
    int b = tM >> 12, n0 = tM & (NPTS - 1);
    #pragma unroll
    for (int i = 0; i < 16; ++i) {
        int e = tid + 256 * i;
        int oo = e >> 6, nn = e & 63;
        out_x5[(size_t)b * 1024 * NPTS + (size_t)(tO + oo) * NPTS + n0 + nn] = t[nn][oo];
    }
}

extern "C" void kernel_launch(void* const* d_in, const int* in_sizes, int n_in,
                              void* d_out, int out_size, void* d_ws, size_t ws_size,
                              hipStream_t stream)
{
    const float* x = (const float*)d_in[0];
    // ec1:1-5  ec2:6-10  ec3:11-15  ec4:16-20  col:21-25  c5:26-30  c6:31-35  c7:36-40  c8:41-42
    const float* ew[4] = {(const float*)d_in[1],  (const float*)d_in[6],  (const float*)d_in[11], (const float*)d_in[16]};
    const float* eg[4] = {(const float*)d_in[2],  (const float*)d_in[7],  (const float*)d_in[12], (const float*)d_in[17]};
    const float* ebp[4]= {(const float*)d_in[3],  (const float*)d_in[8],  (const float*)d_in[13], (const float*)d_in[18]};
    const float* em[4] = {(const float*)d_in[4],  (const float*)d_in[9],  (const float*)d_in[14], (const float*)d_in[19]};
    const float* ev[4] = {(const float*)d_in[5],  (const float*)d_in[10], (const float*)d_in[15], (const float*)d_in[20]};
    const float* col_w = (const float*)d_in[21];
    const float* col_g = (const float*)d_in[22];
    const float* col_b = (const float*)d_in[23];
    const float* col_m = (const float*)d_in[24];
    const float* col_v = (const float*)d_in[25];
    const float* c5_w = (const float*)d_in[26]; const float* c5_g = (const float*)d_in[27];
    const float* c5_b = (const float*)d_in[28]; const float* c5_m = (const float*)d_in[29];
    const float* c5_v = (const float*)d_in[30];
    const float* c6_w = (const float*)d_in[31]; const float* c6_g = (const float*)d_in[32];
    const float* c6_b = (const float*)d_in[33]; const float* c6_m = (const float*)d_in[34];
    const float* c6_v = (const float*)d_in[35];
    const float* c7_w = (const float*)d_in[36]; const float* c7_g = (const float*)d_in[37];
    const float* c7_b = (const float*)d_in[38]; const float* c7_m = (const float*)d_in[39];
    const float* c7_v = (const float*)d_in[40];
    const float* c8_w = (const float*)d_in[41]; const float* c8_b = (const float*)d_in[42];

    // workspace layout (floats). Peak live set: x6 + xcomb = 120 MiB.
    float* ws    = (float*)d_ws;
    float* x6    = ws;                         // [0, 8388608)  (B*N x 512), written at c6
    float* xcomb = ws + 8388608;               // (B*N x 1408): cols 0-383 x_cat, 384-1407 x5
    float* x7    = xcomb;                      // reuse xcomb after c6 (B*N x 256)
    // early-phase aliases inside the (later) x6 region — all dead before c6 runs:
    float* xyzT  = ws;                         // (B*N x 6)      [0, 98304)
    float* xx    = ws + 98304;                 // (B*N)          [98304, 114688)
    int*   idxb  = (int*)(ws + 114688);        // (B*N x 20)     [114688, 442368)
    float* wtbuf = ws + 442368;                // up to 16384    [442368, 458752)

    float* out_logits = (float*)d_out;                               // (B,N,13)
    float* out_x5     = (float*)d_out + (size_t)NBATCH * NPTS * 13;  // (B,1024,N)

    dim3 blk(256);

    k_transpose_in<<<dim3(NTOT/256), blk, 0, stream>>>(x, xyzT);

    // ---- ec1: input xyz (C=3, stride 6) -> xcomb cols 0..63 ----
    k_row_norms<<<dim3(NTOT/256), blk, 0, stream>>>(xyzT, 6, 3, xx);
    k_knn<3><<<dim3(NTOT), blk, 0, stream>>>(xyzT, 6, xx, idxb);
    k_transpose_w<<<dim3((64*6+255)/256), blk, 0, stream>>>(ew[0], wtbuf, 64, 6);
    k_edge_conv<3,64><<<dim3(NTOT), blk, 0, stream>>>(xyzT, 6, idxb, wtbuf,
        eg[0], ebp[0], em[0], ev[0], xcomb + 0, 1408);

    // ---- ec2: x1 (cols 0..63) -> cols 64..127 ----
    k_row_norms<<<dim3(NTOT/256), blk, 0, stream>>>(xcomb + 0, 1408, 64, xx);
    k_knn<64><<<dim3(NTOT), blk, 0, stream>>>(xcomb + 0, 1408, xx, idxb);
    k_transpose_w<<<dim3((64*128+255)/256), blk, 0, stream>>>(ew[1], wtbuf, 64, 128);
    k_edge_conv<64,64><<<dim3(NTOT), blk, 0, stream>>>(xcomb + 0, 1408, idxb, wtbuf,
        eg[1], ebp[1], em[1], ev[1], xcomb + 64, 1408);

    // ---- ec3: x2 (cols 64..127) -> cols 128..191 ----
    k_row_norms<<<dim3(NTOT/256), blk, 0, stream>>>(xcomb + 64, 1408, 64, xx);
    k_knn<64><<<dim3(NTOT), blk, 0, stream>>>(xcomb + 64, 1408, xx, idxb);
    k_transpose_w<<<dim3((64*128+255)/256), blk, 0, stream>>>(ew[2], wtbuf, 64, 128);
    k_edge_conv<64,64><<<dim3(NTOT), blk, 0, stream>>>(xcomb + 64, 1408, idxb, wtbuf,
        eg[2], ebp[2], em[2], ev[2], xcomb + 128, 1408);

    // ---- ec4: x3 (cols 128..191) -> cols 192..319 (O=128) ----
    k_row_norms<<<dim3(NTOT/256), blk, 0, stream>>>(xcomb + 128, 1408, 64, xx);
    k_knn<64><<<dim3(NTOT), blk, 0, stream>>>(xcomb + 128, 1408, xx, idxb);
    k_transpose_w<<<dim3((128*128+255)/256), blk, 0, stream>>>(ew[3], wtbuf, 128, 128);
    k_edge_conv<64,128><<<dim3(NTOT), blk, 0, stream>>>(xcomb + 128, 1408, idxb, wtbuf,
        eg[3], ebp[3], em[3], ev[3], xcomb + 192, 1408);

    // ---- color: rgb -> cols 320..383 ----
    k_color<<<dim3(NTOT*64/256), blk, 0, stream>>>(xyzT, col_w, col_g, col_b, col_m, col_v,
        xcomb + 320, 1408);

    // ---- c5: (384 -> 1024), out into xcomb cols 384..1407 ----
    k_gemm<<<dim3(NTOT/64, 1024/64), blk, 0, stream>>>(xcomb, 1408, c5_w,
        c5_g, c5_b, c5_m, c5_v, 1, xcomb + 384, 1408, 384, 1024);
    k_transpose_x5<<<dim3(NTOT/64, 1024/64), blk, 0, stream>>>(xcomb, out_x5);

    // ---- c6: (1408 -> 512) ----
    k_gemm<<<dim3(NTOT/64, 512/64), blk, 0, stream>>>(xcomb, 1408, c6_w,
        c6_g, c6_b, c6_m, c6_v, 1, x6, 512, 1408, 512);

    // ---- c7: (512 -> 256) ----
    k_gemm<<<dim3(NTOT/64, 256/64), blk, 0, stream>>>(x6, 512, c7_w,
        c7_g, c7_b, c7_m, c7_v, 1, x7, 256, 512, 256);

    // ---- c8: (256 -> 13) + bias, straight into d_out (B,N,13) ----
    k_gemm<<<dim3(NTOT/64, 1), blk, 0, stream>>>(x7, 256, c8_w,
        nullptr, c8_b, nullptr, nullptr, 0, out_logits, 13, 256, 13);
}

// Round 5
// 7376.110 us; speedup vs baseline: 1.0007x; 1.0007x over previous
//
#include <hip/hip_runtime.h>
#include <math.h>

#define NPTS 4096
#define NBATCH 4
#define NTOT (NBATCH*NPTS)
#define KNN 20

__device__ __forceinline__ float lrelu_f(float h) { return h >= 0.f ? h : 0.2f * h; }

// ---------------- x:(B,6,N) -> xyzT:(B*N,6) ----------------
__global__ __launch_bounds__(256) void k_transpose_in(const float* __restrict__ x, float* __restrict__ xyzT)
{
    int p = blockIdx.x * 256 + threadIdx.x;
    if (p >= NTOT) return;
    int b = p >> 12, n = p & (NPTS - 1);
    #pragma unroll
    for (int c = 0; c < 6; ++c)
        xyzT[(size_t)p * 6 + c] = x[((size_t)b * 6 + c) * NPTS + n];
}

// ---------------- row squared norms ----------------
__global__ __launch_bounds__(256) void k_row_norms(const float* __restrict__ f, int stride, int C, float* __restrict__ xx)
{
    int p = blockIdx.x * 256 + threadIdx.x;
    if (p >= NTOT) return;
    const float* r = f + (size_t)p * stride;
    float s = 0.f;
    for (int c = 0; c < C; ++c) { float v = r[c]; s += v * v; }
    xx[p] = s;
}

// ---------------- weight transpose (O,CK) -> (CK,O) ----------------
__global__ __launch_bounds__(256) void k_transpose_w(const float* __restrict__ w, float* __restrict__ wt, int O, int CK)
{
    int e = blockIdx.x * 256 + threadIdx.x;
    if (e >= O * CK) return;
    int c = e / O, o = e - c * O;
    wt[e] = w[(size_t)o * CK + c];
}

// ---------------- kNN: one block per query point ----------------
// pd = 2*dot(q,c) - ||q||^2 - ||c||^2 ; top-20 largest, ties -> lower index
template<int C>
__global__ __launch_bounds__(256) void k_knn(
    const float* __restrict__ feat, int fstride,
    const float* __restrict__ xx,
    int* __restrict__ idx_out)
{
    constexpr int CP = (C + 3) & ~3;
    __shared__ __align__(16) float sq[CP];
    __shared__ float svals[256 * 17];
    __shared__ int   sinds[256 * 17];
    int p = blockIdx.x;
    int b = p >> 12;
    int tid = threadIdx.x;
    const float* qrow = feat + (size_t)p * fstride;
    for (int e = tid; e < C; e += 256) sq[e] = qrow[e];
    __syncthreads();
    float xxq = xx[p];
    const float* fb = feat + (size_t)b * NPTS * fstride;
    const float* xb = xx + b * NPTS;

    // each thread streams 16 candidates, keeps all 16 sorted descending
    float lv[16]; int li[16];
    #pragma unroll
    for (int j = 0; j < 16; ++j) { lv[j] = -INFINITY; li[j] = -1; }
    for (int it = 0; it < 16; ++it) {
        int cand = it * 256 + tid;
        const float* row = fb + (size_t)cand * fstride;
        float dot = 0.f;
        if constexpr ((C & 3) == 0) {
            #pragma unroll
            for (int c4 = 0; c4 < C / 4; ++c4) {
                float4 rv = *(const float4*)(row + 4 * c4);
                float4 qv = *(const float4*)(sq + 4 * c4);
                dot += rv.x * qv.x + rv.y * qv.y + rv.z * qv.z + rv.w * qv.w;
            }
        } else {
            #pragma unroll
            for (int c = 0; c < C; ++c) dot += sq[c] * row[c];
        }
        float cv = 2.f * dot - xxq - xb[cand];
        int ci = cand;
        // strict-greater keeps stable order => equal values keep lower index first
        #pragma unroll
        for (int j = 0; j < 16; ++j) {
            if (cv > lv[j]) {
                float tf = lv[j]; lv[j] = cv; cv = tf;
                int   ti = li[j]; li[j] = ci; ci = ti;
            }
        }
    }
    #pragma unroll
    for (int j = 0; j < 16; ++j) { svals[tid * 17 + j] = lv[j]; sinds[tid * 17 + j] = li[j]; }
    __syncthreads();

    // wave 0 merges the 256 sorted lists: 20 pop rounds
    if (tid < 64) {
        int h0 = 0, h1 = 0, h2 = 0, h3 = 0;
        int base = tid * 4;
        #pragma unroll 1
        for (int r = 0; r < KNN; ++r) {
            float bv = -INFINITY; int bi = 0x7fffffff; int bl = -1;
            if (h0 < 16) { float v = svals[(base+0)*17 + h0]; int ii = sinds[(base+0)*17 + h0]; if (v > bv || (v == bv && ii < bi)) { bv = v; bi = ii; bl = base+0; } }
            if (h1 < 16) { float v = svals[(base+1)*17 + h1]; int ii = sinds[(base+1)*17 + h1]; if (v > bv || (v == bv && ii < bi)) { bv = v; bi = ii; bl = base+1; } }
            if (h2 < 16) { float v = svals[(base+2)*17 + h2]; int ii = sinds[(base+2)*17 + h2]; if (v > bv || (v == bv && ii < bi)) { bv = v; bi = ii; bl = base+2; } }
            if (h3 < 16) { float v = svals[(base+3)*17 + h3]; int ii = sinds[(base+3)*17 + h3]; if (v > bv || (v == bv && ii < bi)) { bv = v; bi = ii; bl = base+3; } }
            #pragma unroll
            for (int off = 32; off > 0; off >>= 1) {
                float ov = __shfl_xor(bv, off);
                int   oi = __shfl_xor(bi, off);
                int   ol = __shfl_xor(bl, off);
                if (ov > bv || (ov == bv && oi < bi)) { bv = ov; bi = oi; bl = ol; }
            }
            if (tid == 0) idx_out[(size_t)p * KNN + r] = bi;
            if ((bl >> 2) == tid) {
                int u = bl & 3;
                h0 += (u == 0); h1 += (u == 1); h2 += (u == 2); h3 += (u == 3);
            }
        }
    }
}

// ---------------- edge conv: one block per point ----------------
// out[o] = lrelu( s[o]*(dot_sel + q[o]) + d[o] ),  dot_sel = max_k (s>=0) or min_k (s<0)
template<int C, int O>
__global__ __launch_bounds__(256) void k_edge_conv(
    const float* __restrict__ in, int istride,
    const int* __restrict__ idx,
    const float* __restrict__ wt,   // (2C, O) transposed weights
    const float* __restrict__ gg, const float* __restrict__ bb,
    const float* __restrict__ mm, const float* __restrict__ vv,
    float* __restrict__ out, int ostride)
{
    constexpr int G = 256 / O;
    constexpr int KPT = KNN / G;
    __shared__ int   sidx[KNN];
    __shared__ float sctr[C];
    __shared__ float snbr[KNN][C];
    __shared__ float sred[2][256];
    int p = blockIdx.x;
    int b = p >> 12;
    int tid = threadIdx.x;
    const float* ctr_row = in + (size_t)p * istride;
    if (tid < KNN) sidx[tid] = idx[(size_t)p * KNN + tid];
    for (int e = tid; e < C; e += 256) sctr[e] = ctr_row[e];
    __syncthreads();
    for (int e = tid; e < KNN * C; e += 256) {
        int k = e / C, c = e - k * C;
        snbr[k][c] = in[((size_t)b * NPTS + sidx[k]) * istride + c];
    }
    __syncthreads();
    int o = tid % O, gid = tid / O;
    float q = 0.f;
    #pragma unroll 4
    for (int c = 0; c < C; ++c) q += (wt[(C + c) * O + o] - wt[c * O + o]) * sctr[c];
    float acc[KPT];
    #pragma unroll
    for (int k = 0; k < KPT; ++k) acc[k] = 0.f;
    #pragma unroll 4
    for (int c = 0; c < C; ++c) {
        float wv = wt[c * O + o];
        #pragma unroll
        for (int k = 0; k < KPT; ++k) acc[k] += wv * snbr[gid * KPT + k][c];
    }
    float mx = -INFINITY, mn = INFINITY;
    #pragma unroll
    for (int k = 0; k < KPT; ++k) { mx = fmaxf(mx, acc[k]); mn = fminf(mn, acc[k]); }
    sred[0][tid] = mx; sred[1][tid] = mn;
    __syncthreads();
    if (gid == 0) {
        #pragma unroll
        for (int g2 = 1; g2 < G; ++g2) { mx = fmaxf(mx, sred[0][g2 * O + o]); mn = fminf(mn, sred[1][g2 * O + o]); }
        float s = gg[o] * rsqrtf(vv[o] + 1e-5f);
        float d = bb[o] - mm[o] * s;
        float dotv = (s >= 0.f) ? mx : mn;
        float h = s * (dotv + q) + d;
        out[(size_t)p * ostride + o] = lrelu_f(h);
    }
}

// ---------------- color MLP (3 -> 64) ----------------
__global__ __launch_bounds__(256) void k_color(
    const float* __restrict__ xyzT,
    const float* __restrict__ w,
    const float* __restrict__ gg, const float* __restrict__ bb,
    const float* __restrict__ mm, const float* __restrict__ vv,
    float* __restrict__ out, int ostride)
{
    int t = blockIdx.x * 256 + threadIdx.x;
    int p = t >> 6, o = t & 63;
    if (p >= NTOT) return;
    const float* rgb = xyzT + (size_t)p * 6 + 3;
    float h = rgb[0] * w[o*3+0] + rgb[1] * w[o*3+1] + rgb[2] * w[o*3+2];
    float s = gg[o] * rsqrtf(vv[o] + 1e-5f);
    float d = bb[o] - mm[o] * s;
    out[(size_t)p * ostride + o] = lrelu_f(s * h + d);
}

// ---------------- fp32 tiled GEMM: out[m][o] = act( A[m][:] . W[o][:] ) ----------------
__global__ __launch_bounds__(256) void k_gemm(
    const float* __restrict__ A, int lda,
    const float* __restrict__ W,
    const float* __restrict__ gg, const float* __restrict__ bb,
    const float* __restrict__ mm, const float* __restrict__ vv,
    int bn_act,
    float* __restrict__ out, int ldo,
    int K, int O)
{
    __shared__ __align__(16) float As[16][68];
    __shared__ __align__(16) float Bs[16][68];
    int tid = threadIdx.x;
    int tM = blockIdx.x * 64;
    int tN = blockIdx.y * 64;
    int lk = tid & 15, lr = tid >> 4;
    float acc[4][4];
    #pragma unroll
    for (int i = 0; i < 4; ++i)
        #pragma unroll
        for (int j = 0; j < 4; ++j) acc[i][j] = 0.f;

    for (int k0 = 0; k0 < K; k0 += 16) {
        #pragma unroll
        for (int i = 0; i < 4; ++i) {
            int r = lr + 16 * i;
            As[lk][r] = A[(size_t)(tM + r) * lda + k0 + lk];
        }
        #pragma unroll
        for (int i = 0; i < 4; ++i) {
            int r = lr + 16 * i;
            int oo = tN + r;
            Bs[lk][r] = (oo < O) ? W[(size_t)oo * K + k0 + lk] : 0.f;
        }
        __syncthreads();
        #pragma unroll
        for (int kk = 0; kk < 16; ++kk) {
            float4 av = *(const float4*)&As[kk][lr * 4];
            float4 bv = *(const float4*)&Bs[kk][lk * 4];
            float a0 = av.x, a1 = av.y, a2 = av.z, a3 = av.w;
            float b0 = bv.x, b1 = bv.y, b2 = bv.z, b3 = bv.w;
            acc[0][0] += a0*b0; acc[0][1] += a0*b1; acc[0][2] += a0*b2; acc[0][3] += a0*b3;
            acc[1][0] += a1*b0; acc[1][1] += a1*b1; acc[1][2] += a1*b2; acc[1][3] += a1*b3;
            acc[2][0] += a2*b0; acc[2][1] += a2*b1; acc[2][2] += a2*b2; acc[2][3] += a2*b3;
            acc[3][0] += a3*b0; acc[3][1] += a3*b1; acc[3][2] += a3*b2; acc[3][3] += a3*b3;
        }
        __syncthreads();
    }
    int ty = lr, tx = lk;
    #pragma unroll
    for (int i = 0; i < 4; ++i) {
        int m = tM + ty * 4 + i;
        #pragma unroll
        for (int j = 0; j < 4; ++j) {
            int oo = tN + tx * 4 + j;
            if (oo < O) {
                float t = acc[i][j];
                if (bn_act) {
                    float s = gg[oo] * rsqrtf(vv[oo] + 1e-5f);
                    float d = bb[oo] - mm[oo] * s;
                    t = s * t + d;
                    t = t >= 0.f ? t : 0.2f * t;
                } else {
                    t += bb[oo];
                }
                out[(size_t)m * ldo + oo] = t;
            }
        }
    }
}

// ---------------- x5 (B*N,1024 cols of xcomb) -> d_out (B,1024,N) ----------------
__global__ __launch_bounds__(256) void k_transpose_x5(const float* __restrict__ xcomb, float* __restrict__ out_x5)
{
    __shared__ float t[64][65];
    int tM = blockIdx.x * 64;
    int tO = blockIdx.y * 64;
    int tid = threadIdx.x;
    #pragma unroll
    for (int i = 0; i < 16; ++i) {
        int e = tid + 256 * i;
        int rr = e >> 6, cc = e & 63;
        t[rr][cc] = xcomb[(size_t)(tM + rr) * 1408 + 384 + tO + cc];
    }
    __syncthreads();
    int b = tM >> 12, n0 = tM & (NPTS - 1);
    #pragma unroll
    for (int i = 0; i < 16; ++i) {
        int e = tid + 256 * i;
        int oo = e >> 6, nn = e & 63;
        out_x5[(size_t)b * 1024 * NPTS + (size_t)(tO + oo) * NPTS + n0 + nn] = t[nn][oo];
    }
}

extern "C" void kernel_launch(void* const* d_in, const int* in_sizes, int n_in,
                              void* d_out, int out_size, void* d_ws, size_t ws_size,
                              hipStream_t stream)
{
    const float* x = (const float*)d_in[0];
    // ec1:1-5  ec2:6-10  ec3:11-15  ec4:16-20  col:21-25  c5:26-30  c6:31-35  c7:36-40  c8:41-42
    const float* ew[4] = {(const float*)d_in[1],  (const float*)d_in[6],  (const float*)d_in[11], (const float*)d_in[16]};
    const float* eg[4] = {(const float*)d_in[2],  (const float*)d_in[7],  (const float*)d_in[12], (const float*)d_in[17]};
    const float* ebp[4]= {(const float*)d_in[3],  (const float*)d_in[8],  (const float*)d_in[13], (const float*)d_in[18]};
    const float* em[4] = {(const float*)d_in[4],  (const float*)d_in[9],  (const float*)d_in[14], (const float*)d_in[19]};
    const float* ev[4] = {(const float*)d_in[5],  (const float*)d_in[10], (const float*)d_in[15], (const float*)d_in[20]};
    const float* col_w = (const float*)d_in[21];
    const float* col_g = (const float*)d_in[22];
    const float* col_b = (const float*)d_in[23];
    const float* col_m = (const float*)d_in[24];
    const float* col_v = (const float*)d_in[25];
    const float* c5_w = (const float*)d_in[26]; const float* c5_g = (const float*)d_in[27];
    const float* c5_b = (const float*)d_in[28]; const float* c5_m = (const float*)d_in[29];
    const float* c5_v = (const float*)d_in[30];
    const float* c6_w = (const float*)d_in[31]; const float* c6_g = (const float*)d_in[32];
    const float* c6_b = (const float*)d_in[33]; const float* c6_m = (const float*)d_in[34];
    const float* c6_v = (const float*)d_in[35];
    const float* c7_w = (const float*)d_in[36]; const float* c7_g = (const float*)d_in[37];
    const float* c7_b = (const float*)d_in[38]; const float* c7_m = (const float*)d_in[39];
    const float* c7_v = (const float*)d_in[40];
    const float* c8_w = (const float*)d_in[41]; const float* c8_b = (const float*)d_in[42];

    // workspace layout (floats). Peak live set: x6 + xcomb = 120 MiB.
    float* ws    = (float*)d_ws;
    float* x6    = ws;                         // [0, 8388608)  (B*N x 512), written at c6
    float* xcomb = ws + 8388608;               // (B*N x 1408): cols 0-383 x_cat, 384-1407 x5
    float* x7    = xcomb;                      // reuse xcomb after c6 (B*N x 256)
    // early-phase aliases inside the (later) x6 region — all dead before c6 runs:
    float* xyzT  = ws;                         // (B*N x 6)      [0, 98304)
    float* xx    = ws + 98304;                 // (B*N)          [98304, 114688)
    int*   idxb  = (int*)(ws + 114688);        // (B*N x 20)     [114688, 442368)
    float* wtbuf = ws + 442368;                // up to 16384    [442368, 458752)

    float* out_logits = (float*)d_out;                               // (B,N,13)
    float* out_x5     = (float*)d_out + (size_t)NBATCH * NPTS * 13;  // (B,1024,N)

    dim3 blk(256);

    k_transpose_in<<<dim3(NTOT/256), blk, 0, stream>>>(x, xyzT);

    // ---- ec1: input xyz (C=3, stride 6) -> xcomb cols 0..63 ----
    k_row_norms<<<dim3(NTOT/256), blk, 0, stream>>>(xyzT, 6, 3, xx);
    k_knn<3><<<dim3(NTOT), blk, 0, stream>>>(xyzT, 6, xx, idxb);
    k_transpose_w<<<dim3((64*6+255)/256), blk, 0, stream>>>(ew[0], wtbuf, 64, 6);
    k_edge_conv<3,64><<<dim3(NTOT), blk, 0, stream>>>(xyzT, 6, idxb, wtbuf,
        eg[0], ebp[0], em[0], ev[0], xcomb + 0, 1408);

    // ---- ec2: x1 (cols 0..63) -> cols 64..127 ----
    k_row_norms<<<dim3(NTOT/256), blk, 0, stream>>>(xcomb + 0, 1408, 64, xx);
    k_knn<64><<<dim3(NTOT), blk, 0, stream>>>(xcomb + 0, 1408, xx, idxb);
    k_transpose_w<<<dim3((64*128+255)/256), blk, 0, stream>>>(ew[1], wtbuf, 64, 128);
    k_edge_conv<64,64><<<dim3(NTOT), blk, 0, stream>>>(xcomb + 0, 1408, idxb, wtbuf,
        eg[1], ebp[1], em[1], ev[1], xcomb + 64, 1408);

    // ---- ec3: x2 (cols 64..127) -> cols 128..191 ----
    k_row_norms<<<dim3(NTOT/256), blk, 0, stream>>>(xcomb + 64, 1408, 64, xx);
    k_knn<64><<<dim3(NTOT), blk, 0, stream>>>(xcomb + 64, 1408, xx, idxb);
    k_transpose_w<<<dim3((64*128+255)/256), blk, 0, stream>>>(ew[2], wtbuf, 64, 128);
    k_edge_conv<64,64><<<dim3(NTOT), blk, 0, stream>>>(xcomb + 64, 1408, idxb, wtbuf,
        eg[2], ebp[2], em[2], ev[2], xcomb + 128, 1408);

    // ---- ec4: x3 (cols 128..191) -> cols 192..319 (O=128) ----
    k_row_norms<<<dim3(NTOT/256), blk, 0, stream>>>(xcomb + 128, 1408, 64, xx);
    k_knn<64><<<dim3(NTOT), blk, 0, stream>>>(xcomb + 128, 1408, xx, idxb);
    k_transpose_w<<<dim3((128*128+255)/256), blk, 0, stream>>>(ew[3], wtbuf, 128, 128);
    k_edge_conv<64,128><<<dim3(NTOT), blk, 0, stream>>>(xcomb + 128, 1408, idxb, wtbuf,
        eg[3], ebp[3], em[3], ev[3], xcomb + 192, 1408);

    // ---- color: rgb -> cols 320..383 ----
    k_color<<<dim3(NTOT*64/256), blk, 0, stream>>>(xyzT, col_w, col_g, col_b, col_m, col_v,
        xcomb + 320, 1408);

    // ---- c5: (384 -> 1024), out into xcomb cols 384..1407 ----
    k_gemm<<<dim3(NTOT/64, 1024/64), blk, 0, stream>>>(xcomb, 1408, c5_w,
        c5_g, c5_b, c5_m, c5_v, 1, xcomb + 384, 1408, 384, 1024);
    k_transpose_x5<<<dim3(NTOT/64, 1024/64), blk, 0, stream>>>(xcomb, out_x5);

    // ---- c6: (1408 -> 512) ----
    k_gemm<<<dim3(NTOT/64, 512/64), blk, 0, stream>>>(xcomb, 1408, c6_w,
        c6_g, c6_b, c6_m, c6_v, 1, x6, 512, 1408, 512);

    // ---- c7: (512 -> 256) ----
    k_gemm<<<dim3(NTOT/64, 256/64), blk, 0, stream>>>(x6, 512, c7_w,
        c7_g, c7_b, c7_m, c7_v, 1, x7, 256, 512, 256);

    // ---- c8: (256 -> 13) + bias, straight into d_out (B,N,13) ----
    k_gemm<<<dim3(NTOT/64, 1), blk, 0, stream>>>(x7, 256, c8_w,
        nullptr, c8_b, nullptr, nullptr, 0, out_logits, 13, 256, 13);
}

// Round 6
// 2511.400 us; speedup vs baseline: 2.9391x; 2.9371x over previous
//
#include <hip/hip_runtime.h>
#include <math.h>

#define NPTS 4096
#define NBATCH 4
#define NTOT (NBATCH*NPTS)
#define KNN 20
#define NCHUNK 8
#define CHUNK (NPTS/NCHUNK)

__device__ __forceinline__ float lrelu_f(float h) { return h >= 0.f ? h : 0.2f * h; }

// ---------------- x:(B,6,N) -> xyzT:(B*N,6) ----------------
__global__ __launch_bounds__(256) void k_transpose_in(const float* __restrict__ x, float* __restrict__ xyzT)
{
    int p = blockIdx.x * 256 + threadIdx.x;
    if (p >= NTOT) return;
    int b = p >> 12, n = p & (NPTS - 1);
    #pragma unroll
    for (int c = 0; c < 6; ++c)
        xyzT[(size_t)p * 6 + c] = x[((size_t)b * 6 + c) * NPTS + n];
}

// ---------------- row squared norms ----------------
__global__ __launch_bounds__(256) void k_row_norms(const float* __restrict__ f, int stride, int C, float* __restrict__ xx)
{
    int p = blockIdx.x * 256 + threadIdx.x;
    if (p >= NTOT) return;
    const float* r = f + (size_t)p * stride;
    float s = 0.f;
    for (int c = 0; c < C; ++c) { float v = r[c]; s += v * v; }
    xx[p] = s;
}

// ---------------- weight transpose (O,CK) -> (CK,O) ----------------
__global__ __launch_bounds__(256) void k_transpose_w(const float* __restrict__ w, float* __restrict__ wt, int O, int CK)
{
    int e = blockIdx.x * 256 + threadIdx.x;
    if (e >= O * CK) return;
    int c = e / O, o = e - c * O;
    wt[e] = w[(size_t)o * CK + c];
}

// ---------------- kNN partial: query-per-thread, candidate chunk per blockIdx.y ----------------
// pd = 2*dot(q,c) - ||q||^2 - ||c||^2 ; per-thread sorted top-20 of its 512-candidate chunk.
// Strict-greater insertion keeps equal values ordered by lower index (candidates processed
// in increasing index), matching jax.lax.top_k tie-breaking after the merge.
template<int C>
__global__ __launch_bounds__(256) void k_knn_part(
    const float* __restrict__ feat, int fstride,
    const float* __restrict__ xx,
    float* __restrict__ pval, int* __restrict__ pidx)
{
    constexpr int C4 = (C + 3) / 4;
    constexpr int TC = 64;                 // candidates staged per LDS tile
    __shared__ __align__(16) float4 sc[TC * C4];
    __shared__ float sxx[TC];
    int tid = threadIdx.x;
    int p = blockIdx.x * 256 + tid;        // global query point
    int b = p >> 12;
    int chunk = blockIdx.y;
    int cbase = chunk * CHUNK;             // candidate base within batch
    const float* fb = feat + (size_t)b * NPTS * fstride;
    const float* xb = xx + b * NPTS;

    // query row -> registers
    float4 qv[C4];
    const float* qrow = feat + (size_t)p * fstride;
    #pragma unroll
    for (int j = 0; j < C4; ++j) qv[j] = *(const float4*)(qrow + 4 * j);
    if constexpr ((C & 3) == 3) qv[C4 - 1].w = 0.f;   // mask pad lane (C=3)
    float xxq = xx[p];

    float lv[KNN]; int li[KNN];
    #pragma unroll
    for (int j = 0; j < KNN; ++j) { lv[j] = -INFINITY; li[j] = 0x7fffffff; }

    for (int t0 = 0; t0 < CHUNK; t0 += TC) {
        __syncthreads();
        for (int e = tid; e < TC * C4; e += 256) {
            int r = e / C4, j = e - r * C4;
            sc[e] = *(const float4*)(fb + (size_t)(cbase + t0 + r) * fstride + 4 * j);
        }
        if (tid < TC) sxx[tid] = xb[cbase + t0 + tid];
        __syncthreads();
        #pragma unroll 4
        for (int cc = 0; cc < TC; ++cc) {
            float ax = 0.f, ay = 0.f, az = 0.f, aw = 0.f;
            #pragma unroll
            for (int j = 0; j < C4; ++j) {
                float4 cv4 = sc[cc * C4 + j];
                ax += qv[j].x * cv4.x; ay += qv[j].y * cv4.y;
                az += qv[j].z * cv4.z; aw += qv[j].w * cv4.w;
            }
            float cv = 2.f * (ax + ay + az + aw) - xxq - sxx[cc];
            if (cv > lv[KNN - 1]) {
                int ci = cbase + t0 + cc;
                #pragma unroll
                for (int j = 0; j < KNN; ++j) {
                    bool sw = cv > lv[j];
                    float tf = lv[j]; int ti = li[j];
                    lv[j] = sw ? cv : lv[j];  li[j] = sw ? ci : li[j];
                    cv    = sw ? tf : cv;     ci    = sw ? ti : ci;
                }
            }
        }
    }
    size_t base = ((size_t)p * NCHUNK + chunk) * KNN;
    #pragma unroll
    for (int j = 0; j < KNN; ++j) { pval[base + j] = lv[j]; pidx[base + j] = li[j]; }
}

// ---------------- kNN merge: one thread per query, 8-way merge of sorted 20-lists ----------------
__global__ __launch_bounds__(256) void k_knn_merge(
    const float* __restrict__ pval, const int* __restrict__ pidx,
    int* __restrict__ idx_out)
{
    int p = blockIdx.x * 256 + threadIdx.x;
    if (p >= NTOT) return;
    const float* pv = pval + (size_t)p * NCHUNK * KNN;
    const int*   pi = pidx + (size_t)p * NCHUNK * KNN;
    float hv[NCHUNK]; int hi_[NCHUNK]; int hp[NCHUNK];
    #pragma unroll
    for (int c = 0; c < NCHUNK; ++c) { hv[c] = pv[c * KNN]; hi_[c] = pi[c * KNN]; hp[c] = 0; }
    #pragma unroll 1
    for (int r = 0; r < KNN; ++r) {
        float bv = hv[0]; int bi = hi_[0]; int bc = 0;
        #pragma unroll
        for (int c = 1; c < NCHUNK; ++c) {
            if (hv[c] > bv || (hv[c] == bv && hi_[c] < bi)) { bv = hv[c]; bi = hi_[c]; bc = c; }
        }
        idx_out[(size_t)p * KNN + r] = bi;
        #pragma unroll
        for (int c = 0; c < NCHUNK; ++c) {
            if (c == bc) {
                hp[c]++;
                if (hp[c] < KNN) { hv[c] = pv[c * KNN + hp[c]]; hi_[c] = pi[c * KNN + hp[c]]; }
                else             { hv[c] = -INFINITY;           hi_[c] = 0x7fffffff; }
            }
        }
    }
}

// ---------------- edge conv: one block per point ----------------
// out[o] = lrelu( s[o]*(dot_sel + q[o]) + d[o] ),  dot_sel = max_k (s>=0) or min_k (s<0)
template<int C, int O>
__global__ __launch_bounds__(256) void k_edge_conv(
    const float* __restrict__ in, int istride,
    const int* __restrict__ idx,
    const float* __restrict__ wt,   // (2C, O) transposed weights
    const float* __restrict__ gg, const float* __restrict__ bb,
    const float* __restrict__ mm, const float* __restrict__ vv,
    float* __restrict__ out, int ostride)
{
    constexpr int G = 256 / O;
    constexpr int KPT = KNN / G;
    __shared__ int   sidx[KNN];
    __shared__ float sctr[C];
    __shared__ float snbr[KNN][C];
    __shared__ float sred[2][256];
    int p = blockIdx.x;
    int b = p >> 12;
    int tid = threadIdx.x;
    const float* ctr_row = in + (size_t)p * istride;
    if (tid < KNN) sidx[tid] = idx[(size_t)p * KNN + tid];
    for (int e = tid; e < C; e += 256) sctr[e] = ctr_row[e];
    __syncthreads();
    for (int e = tid; e < KNN * C; e += 256) {
        int k = e / C, c = e - k * C;
        snbr[k][c] = in[((size_t)b * NPTS + sidx[k]) * istride + c];
    }
    __syncthreads();
    int o = tid % O, gid = tid / O;
    float q = 0.f;
    #pragma unroll 4
    for (int c = 0; c < C; ++c) q += (wt[(C + c) * O + o] - wt[c * O + o]) * sctr[c];
    float acc[KPT];
    #pragma unroll
    for (int k = 0; k < KPT; ++k) acc[k] = 0.f;
    #pragma unroll 4
    for (int c = 0; c < C; ++c) {
        float wv = wt[c * O + o];
        #pragma unroll
        for (int k = 0; k < KPT; ++k) acc[k] += wv * snbr[gid * KPT + k][c];
    }
    float mx = -INFINITY, mn = INFINITY;
    #pragma unroll
    for (int k = 0; k < KPT; ++k) { mx = fmaxf(mx, acc[k]); mn = fminf(mn, acc[k]); }
    sred[0][tid] = mx; sred[1][tid] = mn;
    __syncthreads();
    if (gid == 0) {
        #pragma unroll
        for (int g2 = 1; g2 < G; ++g2) { mx = fmaxf(mx, sred[0][g2 * O + o]); mn = fminf(mn, sred[1][g2 * O + o]); }
        float s = gg[o] * rsqrtf(vv[o] + 1e-5f);
        float d = bb[o] - mm[o] * s;
        float dotv = (s >= 0.f) ? mx : mn;
        float h = s * (dotv + q) + d;
        out[(size_t)p * ostride + o] = lrelu_f(h);
    }
}

// ---------------- color MLP (3 -> 64) ----------------
__global__ __launch_bounds__(256) void k_color(
    const float* __restrict__ xyzT,
    const float* __restrict__ w,
    const float* __restrict__ gg, const float* __restrict__ bb,
    const float* __restrict__ mm, const float* __restrict__ vv,
    float* __restrict__ out, int ostride)
{
    int t = blockIdx.x * 256 + threadIdx.x;
    int p = t >> 6, o = t & 63;
    if (p >= NTOT) return;
    const float* rgb = xyzT + (size_t)p * 6 + 3;
    float h = rgb[0] * w[o*3+0] + rgb[1] * w[o*3+1] + rgb[2] * w[o*3+2];
    float s = gg[o] * rsqrtf(vv[o] + 1e-5f);
    float d = bb[o] - mm[o] * s;
    out[(size_t)p * ostride + o] = lrelu_f(s * h + d);
}

// ---------------- fp32 tiled GEMM: out[m][o] = act( A[m][:] . W[o][:] ) ----------------
__global__ __launch_bounds__(256) void k_gemm(
    const float* __restrict__ A, int lda,
    const float* __restrict__ W,
    const float* __restrict__ gg, const float* __restrict__ bb,
    const float* __restrict__ mm, const float* __restrict__ vv,
    int bn_act,
    float* __restrict__ out, int ldo,
    int K, int O)
{
    __shared__ __align__(16) float As[16][68];
    __shared__ __align__(16) float Bs[16][68];
    int tid = threadIdx.x;
    int tM = blockIdx.x * 64;
    int tN = blockIdx.y * 64;
    int lk = tid & 15, lr = tid >> 4;
    float acc[4][4];
    #pragma unroll
    for (int i = 0; i < 4; ++i)
        #pragma unroll
        for (int j = 0; j < 4; ++j) acc[i][j] = 0.f;

    for (int k0 = 0; k0 < K; k0 += 16) {
        #pragma unroll
        for (int i = 0; i < 4; ++i) {
            int r = lr + 16 * i;
            As[lk][r] = A[(size_t)(tM + r) * lda + k0 + lk];
        }
        #pragma unroll
        for (int i = 0; i < 4; ++i) {
            int r = lr + 16 * i;
            int oo = tN + r;
            Bs[lk][r] = (oo < O) ? W[(size_t)oo * K + k0 + lk] : 0.f;
        }
        __syncthreads();
        #pragma unroll
        for (int kk = 0; kk < 16; ++kk) {
            float4 av = *(const float4*)&As[kk][lr * 4];
            float4 bv = *(const float4*)&Bs[kk][lk * 4];
            float a0 = av.x, a1 = av.y, a2 = av.z, a3 = av.w;
            float b0 = bv.x, b1 = bv.y, b2 = bv.z, b3 = bv.w;
            acc[0][0] += a0*b0; acc[0][1] += a0*b1; acc[0][2] += a0*b2; acc[0][3] += a0*b3;
            acc[1][0] += a1*b0; acc[1][1] += a1*b1; acc[1][2] += a1*b2; acc[1][3] += a1*b3;
            acc[2][0] += a2*b0; acc[2][1] += a2*b1; acc[2][2] += a2*b2; acc[2][3] += a2*b3;
            acc[3][0] += a3*b0; acc[3][1] += a3*b1; acc[3][2] += a3*b2; acc[3][3] += a3*b3;
        }
        __syncthreads();
    }
    int ty = lr, tx = lk;
    #pragma unroll
    for (int i = 0; i < 4; ++i) {
        int m = tM + ty * 4 + i;
        #pragma unroll
        for (int j = 0; j < 4; ++j) {
            int oo = tN + tx * 4 + j;
            if (oo < O) {
                float t = acc[i][j];
                if (bn_act) {
                    float s = gg[oo] * rsqrtf(vv[oo] + 1e-5f);
                    float d = bb[oo] - mm[oo] * s;
                    t = s * t + d;
                    t = t >= 0.f ? t : 0.2f * t;
                } else {
                    t += bb[oo];
                }
                out[(size_t)m * ldo + oo] = t;
            }
        }
    }
}

// ---------------- x5 (B*N,1024 cols of xcomb) -> d_out (B,1024,N) ----------------
__global__ __launch_bounds__(256) void k_transpose_x5(const float* __restrict__ xcomb, float* __restrict__ out_x5)
{
    __shared__ float t[64][65];
    int tM = blockIdx.x * 64;
    int tO = blockIdx.y * 64;
    int tid = threadIdx.x;
    #pragma unroll
    for (int i = 0; i < 16; ++i) {
        int e = tid + 256 * i;
        int rr = e >> 6, cc = e & 63;
        t[rr][cc] = xcomb[(size_t)(tM + rr) * 1408 + 384 + tO + cc];
    }
    __syncthreads();
    int b = tM >> 12, n0 = tM & (NPTS - 1);
    #pragma unroll
    for (int i = 0; i < 16; ++i) {
        int e = tid + 256 * i;
        int oo = e >> 6, nn = e & 63;
        out_x5[(size_t)b * 1024 * NPTS + (size_t)(tO + oo) * NPTS + n0 + nn] = t[nn][oo];
    }
}

extern "C" void kernel_launch(void* const* d_in, const int* in_sizes, int n_in,
                              void* d_out, int out_size, void* d_ws, size_t ws_size,
                              hipStream_t stream)
{
    const float* x = (const float*)d_in[0];
    // ec1:1-5  ec2:6-10  ec3:11-15  ec4:16-20  col:21-25  c5:26-30  c6:31-35  c7:36-40  c8:41-42
    const float* ew[4] = {(const float*)d_in[1],  (const float*)d_in[6],  (const float*)d_in[11], (const float*)d_in[16]};
    const float* eg[4] = {(const float*)d_in[2],  (const float*)d_in[7],  (const float*)d_in[12], (const float*)d_in[17]};
    const float* ebp[4]= {(const float*)d_in[3],  (const float*)d_in[8],  (const float*)d_in[13], (const float*)d_in[18]};
    const float* em[4] = {(const float*)d_in[4],  (const float*)d_in[9],  (const float*)d_in[14], (const float*)d_in[19]};
    const float* ev[4] = {(const float*)d_in[5],  (const float*)d_in[10], (const float*)d_in[15], (const float*)d_in[20]};
    const float* col_w = (const float*)d_in[21];
    const float* col_g = (const float*)d_in[22];
    const float* col_b = (const float*)d_in[23];
    const float* col_m = (const float*)d_in[24];
    const float* col_v = (const float*)d_in[25];
    const float* c5_w = (const float*)d_in[26]; const float* c5_g = (const float*)d_in[27];
    const float* c5_b = (const float*)d_in[28]; const float* c5_m = (const float*)d_in[29];
    const float* c5_v = (const float*)d_in[30];
    const float* c6_w = (const float*)d_in[31]; const float* c6_g = (const float*)d_in[32];
    const float* c6_b = (const float*)d_in[33]; const float* c6_m = (const float*)d_in[34];
    const float* c6_v = (const float*)d_in[35];
    const float* c7_w = (const float*)d_in[36]; const float* c7_g = (const float*)d_in[37];
    const float* c7_b = (const float*)d_in[38]; const float* c7_m = (const float*)d_in[39];
    const float* c7_v = (const float*)d_in[40];
    const float* c8_w = (const float*)d_in[41]; const float* c8_b = (const float*)d_in[42];

    // workspace layout (floats). Peak live set: x6 + xcomb = 120 MiB.
    float* ws    = (float*)d_ws;
    float* x6    = ws;                         // [0, 8388608)  (B*N x 512), written at c6
    float* xcomb = ws + 8388608;               // (B*N x 1408): cols 0-383 x_cat, 384-1407 x5
    float* x7    = xcomb;                      // reuse xcomb after c6 (B*N x 256)
    // early-phase aliases inside the (later) x6 region — all dead before c6 runs:
    float* xyzT  = ws;                         // (B*N x 6)      [0, 98304)
    float* xx    = ws + 98304;                 // (B*N)          [98304, 114688)
    int*   idxb  = (int*)(ws + 114688);        // (B*N x 20)     [114688, 442368)
    float* wtbuf = ws + 442368;                // up to 16384    [442368, 458752)
    float* pval  = ws + 458752;                // (B*N x 8 x 20) [458752, 3080192)
    int*   pidx  = (int*)(ws + 3080192);       // (B*N x 8 x 20) [3080192, 5701632)

    float* out_logits = (float*)d_out;                               // (B,N,13)
    float* out_x5     = (float*)d_out + (size_t)NBATCH * NPTS * 13;  // (B,1024,N)

    dim3 blk(256);
    dim3 knn_grid(NTOT / 256, NCHUNK);

    k_transpose_in<<<dim3(NTOT/256), blk, 0, stream>>>(x, xyzT);

    // ---- ec1: input xyz (C=3, stride 6) -> xcomb cols 0..63 ----
    k_row_norms<<<dim3(NTOT/256), blk, 0, stream>>>(xyzT, 6, 3, xx);
    k_knn_part<3><<<knn_grid, blk, 0, stream>>>(xyzT, 6, xx, pval, pidx);
    k_knn_merge<<<dim3(NTOT/256), blk, 0, stream>>>(pval, pidx, idxb);
    k_transpose_w<<<dim3((64*6+255)/256), blk, 0, stream>>>(ew[0], wtbuf, 64, 6);
    k_edge_conv<3,64><<<dim3(NTOT), blk, 0, stream>>>(xyzT, 6, idxb, wtbuf,
        eg[0], ebp[0], em[0], ev[0], xcomb + 0, 1408);

    // ---- ec2: x1 (cols 0..63) -> cols 64..127 ----
    k_row_norms<<<dim3(NTOT/256), blk, 0, stream>>>(xcomb + 0, 1408, 64, xx);
    k_knn_part<64><<<knn_grid, blk, 0, stream>>>(xcomb + 0, 1408, xx, pval, pidx);
    k_knn_merge<<<dim3(NTOT/256), blk, 0, stream>>>(pval, pidx, idxb);
    k_transpose_w<<<dim3((64*128+255)/256), blk, 0, stream>>>(ew[1], wtbuf, 64, 128);
    k_edge_conv<64,64><<<dim3(NTOT), blk, 0, stream>>>(xcomb + 0, 1408, idxb, wtbuf,
        eg[1], ebp[1], em[1], ev[1], xcomb + 64, 1408);

    // ---- ec3: x2 (cols 64..127) -> cols 128..191 ----
    k_row_norms<<<dim3(NTOT/256), blk, 0, stream>>>(xcomb + 64, 1408, 64, xx);
    k_knn_part<64><<<knn_grid, blk, 0, stream>>>(xcomb + 64, 1408, xx, pval, pidx);
    k_knn_merge<<<dim3(NTOT/256), blk, 0, stream>>>(pval, pidx, idxb);
    k_transpose_w<<<dim3((64*128+255)/256), blk, 0, stream>>>(ew[2], wtbuf, 64, 128);
    k_edge_conv<64,64><<<dim3(NTOT), blk, 0, stream>>>(xcomb + 64, 1408, idxb, wtbuf,
        eg[2], ebp[2], em[2], ev[2], xcomb + 128, 1408);

    // ---- ec4: x3 (cols 128..191) -> cols 192..319 (O=128) ----
    k_row_norms<<<dim3(NTOT/256), blk, 0, stream>>>(xcomb + 128, 1408, 64, xx);
    k_knn_part<64><<<knn_grid, blk, 0, stream>>>(xcomb + 128, 1408, xx, pval, pidx);
    k_knn_merge<<<dim3(NTOT/256), blk, 0, stream>>>(pval, pidx, idxb);
    k_transpose_w<<<dim3((128*128+255)/256), blk, 0, stream>>>(ew[3], wtbuf, 128, 128);
    k_edge_conv<64,128><<<dim3(NTOT), blk, 0, stream>>>(xcomb + 128, 1408, idxb, wtbuf,
        eg[3], ebp[3], em[3], ev[3], xcomb + 192, 1408);

    // ---- color: rgb -> cols 320..383 ----
    k_color<<<dim3(NTOT*64/256), blk, 0, stream>>>(xyzT, col_w, col_g, col_b, col_m, col_v,
        xcomb + 320, 1408);

    // ---- c5: (384 -> 1024), out into xcomb cols 384..1407 ----
    k_gemm<<<dim3(NTOT/64, 1024/64), blk, 0, stream>>>(xcomb, 1408, c5_w,
        c5_g, c5_b, c5_m, c5_v, 1, xcomb + 384, 1408, 384, 1024);
    k_transpose_x5<<<dim3(NTOT/64, 1024/64), blk, 0, stream>>>(xcomb, out_x5);

    // ---- c6: (1408 -> 512) ----
    k_gemm<<<dim3(NTOT/64, 512/64), blk, 0, stream>>>(xcomb, 1408, c6_w,
        c6_g, c6_b, c6_m, c6_v, 1, x6, 512, 1408, 512);

    // ---- c7: (512 -> 256) ----
    k_gemm<<<dim3(NTOT/64, 256/64), blk, 0, stream>>>(x6, 512, c7_w,
        c7_g, c7_b, c7_m, c7_v, 1, x7, 256, 512, 256);

    // ---- c8: (256 -> 13) + bias, straight into d_out (B,N,13) ----
    k_gemm<<<dim3(NTOT/64, 1), blk, 0, stream>>>(x7, 256, c8_w,
        nullptr, c8_b, nullptr, nullptr, 0, out_logits, 13, 256, 13);
}